// Round 9
// baseline (12.532 us; speedup 1.0000x reference)
//
#include <hip/hip_runtime.h>

// PairwiseRankingLoss: B=128 rows, L=1024.
// loss = sum_{b, pos i, neg j} relu(1 - s[b,i] + s[b,j]) / max(num_pairs, 1)
//
// K1: grid = B*SPLIT (SPLIT=8). PER-WAVE ballot compaction: each wave packs
//     its 256 elements into private pos/neg LDS regions (sentinel-padded) --
//     wave-lockstep ordering + disjoint regions => only ONE __syncthreads in
//     the whole kernel. Hot loop: this wave's pos values (registers, KP<=4)
//     against slice s of every wave's compacted negs. Per-WAVE partials go
//     straight to global (no cross-wave reduce); s==0 blocks also store each
//     wave's neg count so K2 can rebuild exact pair counts per row.
// K2: one 256-thread block reduces 4096 wave partials + 512 wave counts.

#define PRL_B 128
#define PRL_L 1024
#define SPLIT 8
#define NBLK  (PRL_B * SPLIT)   // 1024 blocks

// Hot loop over the 4 wave-regions of compacted negs, specialized on K =
// this wave's pos values per lane (wave-uniform 0..4). All indices static.
template<int K>
__device__ __forceinline__ float hotall(const float4* __restrict__ neg4,
                                        int c0_, int c1_, int c2_, int c3_,
                                        int g0_, int g1_, int g2_, int g3_,
                                        float4 pv) {
    float acc[K];
#pragma unroll
    for (int k = 0; k < K; ++k) acc[k] = 0.f;
#pragma unroll
    for (int rw = 0; rw < 4; ++rw) {
        const int c0 = (rw == 0) ? c0_ : (rw == 1) ? c1_ : (rw == 2) ? c2_ : c3_;
        const int c1 = (rw == 0) ? g0_ : (rw == 1) ? g1_ : (rw == 2) ? g2_ : g3_;
        const float4* r4 = neg4 + 64 * rw;
#pragma unroll 2
        for (int c = c0; c < c1; ++c) {
            const float4 d = r4[c];   // wave-uniform LDS broadcast
#pragma unroll
            for (int k = 0; k < K; ++k) {
                const float pk = (k == 0) ? pv.x : (k == 1) ? pv.y
                               : (k == 2) ? pv.z : pv.w;
                acc[k] += (fmaxf(d.x - pk, 0.f) + fmaxf(d.y - pk, 0.f))
                        + (fmaxf(d.z - pk, 0.f) + fmaxf(d.w - pk, 0.f));
            }
        }
    }
    float r = 0.f;
#pragma unroll
    for (int k = 0; k < K; ++k) r += acc[k];
    return r;
}

__global__ __launch_bounds__(256) void prl_partial(
    const float* __restrict__ y_pred,
    const int*   __restrict__ y_true,
    float* __restrict__ wsum,    // [NBLK*4] per-(block,wave) partial sums
    int*   __restrict__ wcnt)    // [PRL_B*4] per-(row,wave) neg counts (s==0)
{
    __shared__ float s_pos[PRL_L];   // 4 wave-regions of 256 (+3e38 pad)
    __shared__ float s_neg[PRL_L];   // 4 wave-regions of 256 (-3e38 pad)
    __shared__ int   s_cnt[4];       // per-wave neg count

    const int blk  = blockIdx.x;
    const int b    = blk >> 3;            // / SPLIT
    const int s    = blk & (SPLIT - 1);
    const int t    = threadIdx.x;
    const int lane = t & 63;
    const int w    = t >> 6;
    const int baseW = 256 * w;

    // Vectorized staging: one float4 + one int4 per thread covers the row.
    const float4 sc = ((const float4*)(y_pred + (size_t)b * PRL_L))[t];
    const int4   lv = ((const int4*)  (y_true + (size_t)b * PRL_L))[t];
    const float sv[4] = {sc.x, sc.y, sc.z, sc.w};
    const int   lb[4] = {lv.x, lv.y, lv.z, lv.w};

    // Sentinel-init own wave's region slot (lane's own float4; overwritten by
    // the scatter below where valid -- same-wave LDS ops are ordered).
    ((float4*)s_pos)[t] = make_float4( 3.0e38f,  3.0e38f,  3.0e38f,  3.0e38f);
    ((float4*)s_neg)[t] = make_float4(-3.0e38f, -3.0e38f, -3.0e38f, -3.0e38f);

    // Per-wave ballot: labels in {0,1} => pos-mask = ~neg-mask.
    unsigned long long mN[4];
    int cN = 0;
#pragma unroll
    for (int r = 0; r < 4; ++r) {
        mN[r] = __ballot(lb[r] == 0);
        cN += (int)__popcll(mN[r]);
    }
    const int cP = 256 - cN;
    if (lane == 0) s_cnt[w] = cN;

    // Scatter into OWN wave region (disjoint across waves -> no barrier yet).
    const unsigned long long lt = (1ULL << lane) - 1ULL;
    int bN = 0, bP = 0;
#pragma unroll
    for (int r = 0; r < 4; ++r) {
        const unsigned long long mn = mN[r], mp = ~mn;
        if (lb[r] == 0) s_neg[baseW + bN + (int)__popcll(mn & lt)] = 1.0f + sv[r];
        else            s_pos[baseW + bP + (int)__popcll(mp & lt)] = sv[r];
        const int pn = (int)__popcll(mn);
        bN += pn;
        bP += 64 - pn;
    }
    __syncthreads();   // the ONLY barrier: regions visible to all waves

    // This wave's pos values (own region, sentinel-padded; 2-way banked read).
    const float4 pv = make_float4(s_pos[baseW + lane],       s_pos[baseW + lane + 64],
                                  s_pos[baseW + lane + 128], s_pos[baseW + lane + 192]);
    const int KP = (cP + 63) >> 6;   // 0..4, wave-uniform

    // Per-region slice bounds for this block's slice s.
    int c0[4], c1[4];
#pragma unroll
    for (int rw = 0; rw < 4; ++rw) {
        const int NG = (s_cnt[rw] + 3) >> 2;        // float4 groups in region
        const int G  = (NG + SPLIT - 1) >> 3;       // groups per slice (SPLIT=8)
        c0[rw] = min(s * G, NG);
        c1[rw] = min(c0[rw] + G, NG);
    }

    float local;
    const float4* neg4 = (const float4*)s_neg;
    switch (KP) {
        case 0:  local = 0.f; break;
        case 1:  local = hotall<1>(neg4, c0[0],c0[1],c0[2],c0[3], c1[0],c1[1],c1[2],c1[3], pv); break;
        case 2:  local = hotall<2>(neg4, c0[0],c0[1],c0[2],c0[3], c1[0],c1[1],c1[2],c1[3], pv); break;
        case 3:  local = hotall<3>(neg4, c0[0],c0[1],c0[2],c0[3], c1[0],c1[1],c1[2],c1[3], pv); break;
        default: local = hotall<4>(neg4, c0[0],c0[1],c0[2],c0[3], c1[0],c1[1],c1[2],c1[3], pv); break;
    }

    // Wave-only reduction; per-wave partial straight to global.
#pragma unroll
    for (int off = 32; off >= 1; off >>= 1)
        local += __shfl_down(local, off, 64);
    if (lane == 0) {
        wsum[blk * 4 + w] = local;
        if (s == 0) wcnt[b * 4 + w] = cN;   // exact per-(row,wave) neg count
    }
}

// One 256-thread block: reduce 4096 wave partials + rebuild exact pair count.
__global__ __launch_bounds__(256) void prl_finalize(
    const float* __restrict__ wsum,   // [NBLK*4]
    const int*   __restrict__ wcnt,   // [PRL_B*4]
    float* __restrict__ out)
{
    __shared__ float s_s[4];
    __shared__ int   s_p[4];
    const int t = threadIdx.x, lane = t & 63, w = t >> 6;

    const float4* s4 = (const float4*)wsum;
    float fs = 0.f;
#pragma unroll
    for (int k = 0; k < 4; ++k) {        // 256 threads x 4 float4 = 4096
        const float4 a = s4[t + 256 * k];
        fs += (a.x + a.y) + (a.z + a.w);
    }
    int ps = 0;
    if (t < PRL_B) {                     // one row per thread
        const int4 c = ((const int4*)wcnt)[t];
        const int nn = (c.x + c.y) + (c.z + c.w);
        ps = (PRL_L - nn) * nn;          // <= 262144/row; total < 2^31
    }
#pragma unroll
    for (int off = 32; off >= 1; off >>= 1) {
        fs += __shfl_down(fs, off, 64);
        ps += __shfl_down(ps, off, 64);
    }
    if (lane == 0) { s_s[w] = fs; s_p[w] = ps; }
    __syncthreads();
    if (t == 0) {
        const float total = (s_s[0] + s_s[1]) + (s_s[2] + s_s[3]);
        const int   pairs = (s_p[0] + s_p[1]) + (s_p[2] + s_p[3]);
        out[0] = (pairs > 0) ? (total / fmaxf((float)pairs, 1.0f)) : total;
    }
}

extern "C" void kernel_launch(void* const* d_in, const int* in_sizes, int n_in,
                              void* d_out, int out_size, void* d_ws, size_t ws_size,
                              hipStream_t stream) {
    const float* y_pred = (const float*)d_in[0];
    const int*   y_true = (const int*)d_in[1];
    float* out = (float*)d_out;

    // ws layout: float wsum[NBLK*4] (16 KB); int wcnt[PRL_B*4] (2 KB)
    float* wsum = (float*)d_ws;
    int*   wcnt = (int*)((char*)d_ws + NBLK * 4 * sizeof(float));

    prl_partial<<<NBLK, 256, 0, stream>>>(y_pred, y_true, wsum, wcnt);
    prl_finalize<<<1, 256, 0, stream>>>(wsum, wcnt, out);
}

// Round 10
// 12.105 us; speedup vs baseline: 1.0352x; 1.0352x over previous
//
#include <hip/hip_runtime.h>

// PairwiseRankingLoss: B=128 rows, L=1024.
// loss = sum_{b, pos i, neg j} relu(1 - s[b,i] + s[b,j]) / max(num_pairs, 1)
//
// K1: grid = B*SPLIT (SPLIT=8). Per-block ballot compaction (R6 structure,
//     best measured) into dense pos[]/neg[] LDS arrays. Hot loop is now a
//     STATIC 18-group slice (8*18=144 groups covers any realistic nn; the
//     sentinel-padded groups contribute exactly 0) -> full unroll, all 18
//     ds_read_b128 issued up-front, one lgkmcnt wait instead of 8 exposed
//     ~120cy LDS stalls. Rare tail (nn>576) handled by a dynamic loop on
//     slice 7 (trip count 0 in practice).
// K2: one 64-thread wave reduces the 1024 partials and writes the loss.

#define PRL_B 128
#define PRL_L 1024
#define SPLIT 8
#define NBLK  (PRL_B * SPLIT)   // 1024 blocks
#define GSTAT 18                // static float4-groups per slice

// Hot loop specialized on K = pos values per thread (block-uniform runtime).
// Static GSTAT-group main body + (normally empty) dynamic tail.
template<int K>
__device__ __forceinline__ float hotloop(const float4* __restrict__ d4,
                                         int c0, int t0, int t1, float4 pv) {
    float acc[K];
#pragma unroll
    for (int k = 0; k < K; ++k) acc[k] = 0.f;
#pragma unroll
    for (int c = 0; c < GSTAT; ++c) {
        const float4 d = d4[c0 + c];   // wave-uniform LDS broadcast, static ofs
#pragma unroll
        for (int k = 0; k < K; ++k) {
            const float pk = (k == 0) ? pv.x : (k == 1) ? pv.y : (k == 2) ? pv.z : pv.w;
            acc[k] += (fmaxf(d.x - pk, 0.f) + fmaxf(d.y - pk, 0.f))
                    + (fmaxf(d.z - pk, 0.f) + fmaxf(d.w - pk, 0.f));
        }
    }
    for (int c = t0; c < t1; ++c) {    // tail: only if nn > 4*SPLIT*GSTAT
        const float4 d = d4[c];
#pragma unroll
        for (int k = 0; k < K; ++k) {
            const float pk = (k == 0) ? pv.x : (k == 1) ? pv.y : (k == 2) ? pv.z : pv.w;
            acc[k] += (fmaxf(d.x - pk, 0.f) + fmaxf(d.y - pk, 0.f))
                    + (fmaxf(d.z - pk, 0.f) + fmaxf(d.w - pk, 0.f));
        }
    }
    float r = 0.f;
#pragma unroll
    for (int k = 0; k < K; ++k) r += acc[k];
    return r;
}

__global__ __launch_bounds__(256, 4) void prl_partial(
    const float* __restrict__ y_pred,
    const int*   __restrict__ y_true,
    float* __restrict__ bsum,    // [NBLK]
    int*   __restrict__ bpairs)  // [NBLK]
{
    __shared__ float4 s_pos4[PRL_L / 4];   // compacted pos scores (+3e38 pad)
    __shared__ float4 s_neg4[PRL_L / 4];   // compacted 1+neg scores (-3e38 pad)
    __shared__ int    s_cntP[4];
    __shared__ float  s_wsum[4];
    float* s_pos = (float*)s_pos4;
    float* s_neg = (float*)s_neg4;

    const int blk  = blockIdx.x;
    const int b    = blk >> 3;            // / SPLIT
    const int s    = blk & (SPLIT - 1);
    const int t    = threadIdx.x;
    const int lane = t & 63;
    const int w    = t >> 6;

    // Vectorized staging: one float4 + one int4 per thread covers the row.
    // Element e = 256*w + 4*lane + r.
    const float4 sc = ((const float4*)(y_pred + (size_t)b * PRL_L))[t];
    const int4   lv = ((const int4*)  (y_true + (size_t)b * PRL_L))[t];
    const float sv[4] = {sc.x, sc.y, sc.z, sc.w};
    const int   lb[4] = {lv.x, lv.y, lv.z, lv.w};

    // Pass 1: per-wave pos masks via ballot; labels in {0,1} => neg = ~pos.
    unsigned long long mP[4];
    int cP = 0;
#pragma unroll
    for (int r = 0; r < 4; ++r) {
        mP[r] = __ballot(lb[r] == 1);
        cP += (int)__popcll(mP[r]);
    }
    if (lane == 0) s_cntP[w] = cP;

    // Sentinel-init (pad regions survive; valid regions overwritten below).
    s_pos4[t] = make_float4( 3.0e38f,  3.0e38f,  3.0e38f,  3.0e38f);
    s_neg4[t] = make_float4(-3.0e38f, -3.0e38f, -3.0e38f, -3.0e38f);
    __syncthreads();

    // Wave offsets + row totals (np; nn = L - np).
    int offP = 0, np = 0;
#pragma unroll
    for (int ww = 0; ww < 4; ++ww) {
        const int p_ = s_cntP[ww];
        np += p_;
        if (ww < w) offP += p_;
    }
    const int nn   = PRL_L - np;
    const int offN = 256 * w - offP;

    // Pass 2: scatter compacted values (order irrelevant).
    const unsigned long long lt = (1ULL << lane) - 1ULL;
    int bP = offP, bN = offN;
#pragma unroll
    for (int r = 0; r < 4; ++r) {
        const unsigned long long mp = mP[r], mn = ~mp;
        if (lb[r] == 1) s_pos[bP + (int)__popcll(mp & lt)] = sv[r];
        else            s_neg[bN + (int)__popcll(mn & lt)] = 1.0f + sv[r];
        bP += (int)__popcll(mp);
        bN += 64 - (int)__popcll(mp);
    }
    __syncthreads();

    // This thread's pos values (sentinel-padded reads are safe).
    const float4 pv = make_float4(s_pos[t], s_pos[t + 256],
                                  s_pos[t + 512], s_pos[t + 768]);
    const int KP  = (np + 255) >> 8;              // 0..4, block-uniform
    const int NN4 = (nn + 3) >> 2;                // float4 groups of negs

    // Static slice [s*GSTAT, s*GSTAT+GSTAT); sentinels past NN4 contribute 0.
    const int c0 = s * GSTAT;                     // max 7*18+18 = 144 <= 256
    int t0 = 0, t1 = 0;
    if (s == SPLIT - 1 && NN4 > SPLIT * GSTAT) {  // nn > 576: rare tail
        t0 = SPLIT * GSTAT;
        t1 = NN4;
    }

    float local;
    const float4* neg4 = (const float4*)s_neg4;
    switch (KP) {
        case 0:  local = 0.f; break;
        case 1:  local = hotloop<1>(neg4, c0, t0, t1, pv); break;
        case 2:  local = hotloop<2>(neg4, c0, t0, t1, pv); break;
        case 3:  local = hotloop<3>(neg4, c0, t0, t1, pv); break;
        default: local = hotloop<4>(neg4, c0, t0, t1, pv); break;
    }

    // Block reduction (sum only; pair count is uniform, no reduce needed).
#pragma unroll
    for (int off = 32; off >= 1; off >>= 1)
        local += __shfl_down(local, off, 64);
    if (lane == 0) s_wsum[w] = local;
    __syncthreads();

    if (t == 0) {
        bsum[blk]   = (s_wsum[0] + s_wsum[1]) + (s_wsum[2] + s_wsum[3]);
        bpairs[blk] = (s == 0) ? np * nn : 0;   // exact pair count, once/row
    }
}

// Single-wave finalize: 64 threads read all 1024 partials (8 KB).
__global__ __launch_bounds__(64) void prl_finalize(
    const float* __restrict__ bsum,
    const int*   __restrict__ bpairs,
    float* __restrict__ out)
{
    const int t = threadIdx.x;
    const float4* s4 = (const float4*)bsum;
    const int4*   p4 = (const int4*)bpairs;

    float fs = 0.f; int ps = 0;
#pragma unroll
    for (int k = 0; k < 4; ++k) {           // 4 x 64 float4 = 1024 partials
        const float4 a = s4[t + 64 * k];
        const int4  ia = p4[t + 64 * k];
        fs += (a.x + a.y) + (a.z + a.w);
        ps += (ia.x + ia.y) + (ia.z + ia.w);
    }
#pragma unroll
    for (int off = 32; off >= 1; off >>= 1) {
        fs += __shfl_down(fs, off, 64);
        ps += __shfl_down(ps, off, 64);
    }
    if (t == 0)
        out[0] = (ps > 0) ? (fs / fmaxf((float)ps, 1.0f)) : fs;
}

extern "C" void kernel_launch(void* const* d_in, const int* in_sizes, int n_in,
                              void* d_out, int out_size, void* d_ws, size_t ws_size,
                              hipStream_t stream) {
    const float* y_pred = (const float*)d_in[0];
    const int*   y_true = (const int*)d_in[1];
    float* out = (float*)d_out;

    // ws layout: float bsum[NBLK]; int bpairs[NBLK]
    float* bsum   = (float*)d_ws;
    int*   bpairs = (int*)((char*)d_ws + NBLK * sizeof(float));

    prl_partial<<<NBLK, 256, 0, stream>>>(y_pred, y_true, bsum, bpairs);
    prl_finalize<<<1, 64, 0, stream>>>(bsum, bpairs, out);
}